// Round 10
// baseline (167.323 us; speedup 1.0000x reference)
//
#include <hip/hip_runtime.h>
#include <math.h>

// Problem constants: N=128, LQ=LK=64, D=512, H=8 (head split is a no-op in the einsum).
#define DN 512          // feature dim
#define NB 128          // batch N

typedef unsigned short ushort_t;
typedef __attribute__((ext_vector_type(8))) short bf16x8;
typedef __attribute__((ext_vector_type(4))) float f32x4;

static __device__ __forceinline__ ushort_t f2bf(float f){
  unsigned u = __float_as_uint(f);
  u += 0x7fffu + ((u >> 16) & 1u);   // round-to-nearest-even
  return (ushort_t)(u >> 16);
}

// async global->LDS, 16B per lane; LDS dest is wave-uniform base + lane*16
#define GLL16(gp, lp)                                                          \
  __builtin_amdgcn_global_load_lds(                                            \
      (const __attribute__((address_space(1))) void*)(gp),                     \
      (__attribute__((address_space(3))) void*)(lp), 16, 0, 0)

#define BAR() __builtin_amdgcn_s_barrier()
#define SCHED0() __builtin_amdgcn_sched_barrier(0)
#define VMC(N)                                                                 \
  do {                                                                         \
    asm volatile("s_waitcnt vmcnt(" #N ")" ::: "memory");                      \
  } while (0)

// ---------------------------------------------------------------------------
// Projections (both Q and K in one launch; z selects). Out = X @ W^T + bias,
// 128x128 tile, BK=64, 4 waves. LDS uses 16B-slot XOR swizzle (slot ^= row&7).
__global__ __launch_bounds__(256) void proj_kernel(const float* __restrict__ Xq,
                                                   const float* __restrict__ Wq,
                                                   const float* __restrict__ bq,
                                                   ushort_t* __restrict__ Oq,
                                                   const float* __restrict__ Xk,
                                                   const float* __restrict__ Wk,
                                                   const float* __restrict__ bk,
                                                   ushort_t* __restrict__ Ok) {
  const float* X = blockIdx.z ? Xk : Xq;
  const float* W = blockIdx.z ? Wk : Wq;
  const float* bias = blockIdx.z ? bk : bq;
  ushort_t* Out = blockIdx.z ? Ok : Oq;

  __shared__ __align__(16) ushort_t As[128 * 64];
  __shared__ __align__(16) ushort_t Bs[128 * 64];
  const int tid = threadIdx.x;
  const int wave = tid >> 6, lane = tid & 63;
  const int wr = wave >> 1, wc = wave & 1;
  const int m0 = blockIdx.y * 128, n0 = blockIdx.x * 128;
  const int arow = lane & 15, g = lane >> 4;

  f32x4 acc[4][4] = {};

  for (int kt = 0; kt < 8; ++kt) {
    const int k0 = kt * 64;
#pragma unroll
    for (int i = 0; i < 8; i++) {
      int e = i * 1024 + tid * 4;
      int r = e >> 6, c = e & 63;
      int cs = ((((c >> 3) ^ (r & 7)) << 3) | (c & 7));
      float4 va = *(const float4*)&X[(size_t)(m0 + r) * DN + k0 + c];
      ushort4 ha;
      ha.x = f2bf(va.x); ha.y = f2bf(va.y); ha.z = f2bf(va.z); ha.w = f2bf(va.w);
      *(ushort4*)&As[r * 64 + cs] = ha;
      float4 vb = *(const float4*)&W[(size_t)(n0 + r) * DN + k0 + c];
      ushort4 hb;
      hb.x = f2bf(vb.x); hb.y = f2bf(vb.y); hb.z = f2bf(vb.z); hb.w = f2bf(vb.w);
      *(ushort4*)&Bs[r * 64 + cs] = hb;
    }
    __syncthreads();

    bf16x8 af[4][2], bfr[4][2];
#pragma unroll
    for (int mi = 0; mi < 4; mi++)
#pragma unroll
      for (int ks = 0; ks < 2; ks++)
        af[mi][ks] = *(const bf16x8*)&As[(wr * 64 + mi * 16 + arow) * 64 +
                                         ((((ks << 2) | g) ^ (arow & 7)) << 3)];
#pragma unroll
    for (int ni = 0; ni < 4; ni++)
#pragma unroll
      for (int ks = 0; ks < 2; ks++)
        bfr[ni][ks] = *(const bf16x8*)&Bs[(wc * 64 + ni * 16 + arow) * 64 +
                                          ((((ks << 2) | g) ^ (arow & 7)) << 3)];
#pragma unroll
    for (int ks = 0; ks < 2; ks++)
#pragma unroll
      for (int mi = 0; mi < 4; mi++)
#pragma unroll
        for (int ni = 0; ni < 4; ni++)
          acc[mi][ni] = __builtin_amdgcn_mfma_f32_16x16x32_bf16(
              af[mi][ks], bfr[ni][ks], acc[mi][ni], 0, 0, 0);
    __syncthreads();
  }

  float bc[4];
#pragma unroll
  for (int ni = 0; ni < 4; ni++) bc[ni] = bias[n0 + wc * 64 + ni * 16 + arow];
#pragma unroll
  for (int mi = 0; mi < 4; mi++)
#pragma unroll
    for (int ni = 0; ni < 4; ni++)
#pragma unroll
      for (int j = 0; j < 4; j++) {
        int row = m0 + wr * 64 + mi * 16 + (lane >> 4) * 4 + j;
        int col = n0 + wc * 64 + ni * 16 + arow;
        Out[(size_t)row * DN + col] = f2bf(acc[mi][ni][j] + bc[ni]);
      }
}

// ---------------------------------------------------------------------------
// Pairwise logits + fused max/sum reductions.
// Grid 256 (1 block/CU, zero restarts). Block (by 0..31, bxg 0..7) sweeps 4
// b-tiles bxt = bxg*4+bxi as ONE continuous 32-K-tile pipeline built from the
// r9 rolled TILE body (proven no-spill, pointer-bump staging). Per-b-tile
// epilogue between tiles; staging for the next b-tile stays in flight across
// it. XCD map: each XCD gets 4 by x 8 bxg (A 2MB resident x8 reuse, B x4).
__global__ __launch_bounds__(512, 2) void pairs_kernel(const ushort_t* __restrict__ Q,
                                                       const ushort_t* __restrict__ Km,
                                                       const float* __restrict__ amask,
                                                       const float* __restrict__ ls_ptr,
                                                       float* __restrict__ out) {
  __shared__ __align__(16) ushort_t lds[2 * 2 * 256 * 64];  // 128 KiB
  const int tid = threadIdx.x;
  const int wave = tid >> 6, lane = tid & 63;
  const int wr = wave >> 2, wc = wave & 3;      // 2M x 4N wave grid
  const int arow = lane & 15, g = lane >> 4;

  const int bid = blockIdx.x;
  const int xcd = bid & 7, idx = bid >> 3;       // 32 blocks per XCD
  const int by = xcd * 4 + (idx >> 3);           // 0..31
  const int bxg = idx & 7;                       // 0..7

  const int l8 = lane >> 3, l7 = lane & 7;
  const int srcSlot = l7 ^ l8;

  // epilogue scalars first; drain their vmem so pipeline vmcnt counts are exact
  const float lsv = expf(ls_ptr[0]);
  float am2[2];
#pragma unroll
  for (int ph = 0; ph < 2; ph++) {
    float am = amask[(by * 4 + wr * 2 + ph) * 64 + lane];
#pragma unroll
    for (int off = 1; off < 64; off <<= 1) am += __shfl_xor(am, off);
    am2[ph] = am;
  }
  VMC(0); SCHED0();

  f32x4 acc[8][4] = {};
  bf16x8 aA[4], aB[4], bR0[4], bR1[4];

  // staging pointers: advance +64 elems per staged K-tile; rollover at k=7
  const ushort_t* pA = Q + (size_t)(by * 256 + (wave >> 2) * 128 + (wave & 3) * 16 + l8) * DN + srcSlot * 8;
  const ushort_t* pB = Km + (size_t)(bxg * 4 * 256 + wave * 16 + l8) * DN + srcSlot * 8;
  const int sAr = (wave >> 2) * 128 + (wave & 3) * 16;   // LDS A row base
  const int sBr = wave * 16;                             // LDS B row base

  // per-lane ds_read element offsets within a 256x64 region
  const int aoff0 = arow * 64 + ((((0 << 2) | g) ^ (arow & 7)) << 3);
  const int aoff1 = arow * 64 + ((((1 << 2) | g) ^ (arow & 7)) << 3);

#define SAu(u, dn)                                                             \
  {                                                                            \
    GLL16(pA + ((u) * 64 + 0) * DN, &lds[(((dn) * 2 + 0) * 256 + sAr + (u) * 64 + 0) * 64]); \
    GLL16(pA + ((u) * 64 + 8) * DN, &lds[(((dn) * 2 + 0) * 256 + sAr + (u) * 64 + 8) * 64]); \
  }
#define SBh(h, dn)                                                             \
  {                                                                            \
    GLL16(pB + ((h) * 128 + 0) * DN, &lds[(((dn) * 2 + 1) * 256 + sBr + (h) * 128 + 0) * 64]); \
    GLL16(pB + ((h) * 128 + 8) * DN, &lds[(((dn) * 2 + 1) * 256 + sBr + (h) * 128 + 8) * 64]); \
  }
#define LDBx(br, dd, ao)                                                       \
  _Pragma("unroll")                                                            \
  for (int ni = 0; ni < 4; ni++)                                               \
    br[ni] = *(const bf16x8*)&lds[((dd) * 2 + 1) * 16384 + (wc * 64 + ni * 16) * 64 + (ao)];
#define LDAx(ar, mh, dd, ao)                                                   \
  _Pragma("unroll")                                                            \
  for (int mi = 0; mi < 4; mi++)                                               \
    ar[mi] = *(const bf16x8*)&lds[((dd) * 2 + 0) * 16384 + (wr * 128 + (mh) * 64 + mi * 16) * 64 + (ao)];
#define MMAx(mh, ar, br)                                                       \
  {                                                                            \
    __builtin_amdgcn_s_setprio(1);                                             \
    _Pragma("unroll")                                                          \
    for (int mi = 0; mi < 4; mi++)                                             \
      _Pragma("unroll")                                                        \
      for (int ni = 0; ni < 4; ni++)                                           \
        acc[(mh) * 4 + mi][ni] = __builtin_amdgcn_mfma_f32_16x16x32_bf16(      \
            ar[mi], br[ni], acc[(mh) * 4 + mi][ni], 0, 0, 0);                  \
    __builtin_amdgcn_s_setprio(0);                                             \
  }
  // One K-tile (d literal; DO_STAGE stages the next tile; MIDW/BOTW = vmcnt tokens)
#define TILE(dlit, DO_STAGE, MIDW, BOTW)                                       \
  {                                                                            \
    if (DO_STAGE) {                                                            \
      SBh(0, (dlit) ^ 1); SBh(1, (dlit) ^ 1);                                  \
      SAu(0, (dlit) ^ 1); SAu(1, (dlit) ^ 1);                                  \
      pA += 64; pB += 64;                                                      \
    }                                                                          \
    LDBx(bR0, dlit, aoff0); LDBx(bR1, dlit, aoff1);                            \
    LDAx(aA, 0, dlit, aoff0); MMAx(0, aA, bR0);                                \
    LDAx(aB, 0, dlit, aoff1); MMAx(0, aB, bR1);                                \
    MIDW; BAR();                                                               \
    LDAx(aA, 1, dlit, aoff0); MMAx(1, aA, bR0);                                \
    LDAx(aB, 1, dlit, aoff1); MMAx(1, aB, bR1);                                \
    BOTW; BAR(); SCHED0();                                                     \
  }

  // prologue: stage tile (bxi=0,k=0); validate {B,B,A-u0}, leave A-u1 in flight
  SBh(0, 0); SBh(1, 0); SAu(0, 0); SAu(1, 0);
  pA += 64; pB += 64;
  VMC(2);
  BAR(); SCHED0();

  // steady state: enter tile with 2 outstanding (own A-u1 [+2 epilogue stores
  // at b-tile boundaries]); stage 8 for next; VMC(8) validates own A-u1;
  // VMC(2) validates next tile's {B,B,A-u0}, leaves its A-u1 in flight.
#pragma unroll 1
  for (int bxi = 0; bxi < 4; ++bxi) {
#pragma unroll 1
    for (int kk = 0; kk < 3; ++kk) {
      TILE(0, true, VMC(8), VMC(2));   // k = 2*kk
      TILE(1, true, VMC(8), VMC(2));   // k = 2*kk+1
    }
    // k = 6: stages (bxi,7); then roll pointers over to (bxi+1, 0)
    TILE(0, true, VMC(8), VMC(2));
    pA -= 512;
    pB += 256 * DN - 512;
    // k = 7: stages (bxi+1, 0) [except the very last tile]
    if (bxi < 3) {
      TILE(1, true, VMC(8), VMC(2));
    } else {
      TILE(1, false, VMC(0), VMC(0));
    }

    // ---- per-b-tile epilogue: two (a,b) pairs per wave ----
    // C/D layout: col = lane&15, row = (lane>>4)*4 + reg.
    const int bxt = bxg * 4 + bxi;
#pragma unroll
    for (int ph = 0; ph < 2; ph++) {
      float t2v = 0.f;
#pragma unroll
      for (int mi = ph * 4; mi < ph * 4 + 4; mi++) {
        f32x4 rm = acc[mi][0];
#pragma unroll
        for (int ni = 1; ni < 4; ni++)
#pragma unroll
          for (int j = 0; j < 4; j++) rm[j] = fmaxf(rm[j], acc[mi][ni][j]);
#pragma unroll
        for (int off = 1; off < 16; off <<= 1)
#pragma unroll
          for (int j = 0; j < 4; j++) rm[j] = fmaxf(rm[j], __shfl_xor(rm[j], off));
        t2v += rm[0] + rm[1] + rm[2] + rm[3];
      }
      t2v += __shfl_xor(t2v, 16);
      t2v += __shfl_xor(t2v, 32);

      float v2t = 0.f;
#pragma unroll
      for (int ni = 0; ni < 4; ni++) {
        float cm = -INFINITY;
#pragma unroll
        for (int mi = ph * 4; mi < ph * 4 + 4; mi++)
#pragma unroll
          for (int j = 0; j < 4; j++) cm = fmaxf(cm, acc[mi][ni][j]);
        cm = fmaxf(cm, __shfl_xor(cm, 16));
        cm = fmaxf(cm, __shfl_xor(cm, 32));
        v2t += cm;
      }
#pragma unroll
      for (int off = 1; off < 16; off <<= 1) v2t += __shfl_xor(v2t, off);

      const int a = by * 4 + wr * 2 + ph, b = bxt * 4 + wc;
      float r = lsv * 0.5f * (t2v / am2[ph] + v2t / 64.0f);
      if (lane == 0) {
        out[a * NB + b] = r;                 // r
        out[NB * NB + b * NB + a] = r;       // r.T
      }
    }
    // reset accumulators for the next b-tile
#pragma unroll
    for (int i = 0; i < 8; i++)
#pragma unroll
      for (int j = 0; j < 4; j++) acc[i][j] = f32x4{0.f, 0.f, 0.f, 0.f};
  }
}

// ---------------------------------------------------------------------------
extern "C" void kernel_launch(void* const* d_in, const int* in_sizes, int n_in,
                              void* d_out, int out_size, void* d_ws, size_t ws_size,
                              hipStream_t stream) {
  const float* query = (const float*)d_in[0];
  const float* key   = (const float*)d_in[1];
  const float* amask = (const float*)d_in[2];
  const float* Wq    = (const float*)d_in[3];
  const float* bq    = (const float*)d_in[4];
  const float* Wk    = (const float*)d_in[5];
  const float* bk    = (const float*)d_in[6];
  const float* ls    = (const float*)d_in[7];

  char* ws = (char*)d_ws;
  ushort_t* Qb = (ushort_t*)(ws);                      // 8 MB
  ushort_t* Kb = (ushort_t*)(ws + 8 * 1024 * 1024);    // 8 MB

  proj_kernel<<<dim3(4, 64, 2), 256, 0, stream>>>(query, Wq, bq, Qb, key, Wk, bk, Kb);
  pairs_kernel<<<dim3(256), 512, 0, stream>>>(Qb, Kb, amask, ls, (float*)d_out);
}

// Round 11
// 114.403 us; speedup vs baseline: 1.4626x; 1.4626x over previous
//
#include <hip/hip_runtime.h>
#include <math.h>

// Problem constants: N=128, LQ=LK=64, D=512, H=8 (head split is a no-op in the einsum).
#define DN 512          // feature dim
#define NB 128          // batch N

typedef unsigned short ushort_t;
typedef __attribute__((ext_vector_type(8))) short bf16x8;
typedef __attribute__((ext_vector_type(4))) float f32x4;

static __device__ __forceinline__ ushort_t f2bf(float f){
  unsigned u = __float_as_uint(f);
  u += 0x7fffu + ((u >> 16) & 1u);   // round-to-nearest-even
  return (ushort_t)(u >> 16);
}

// async global->LDS, 16B per lane; LDS dest is wave-uniform base + lane*16
#define GLL16(gp, lp)                                                          \
  __builtin_amdgcn_global_load_lds(                                            \
      (const __attribute__((address_space(1))) void*)(gp),                     \
      (__attribute__((address_space(3))) void*)(lp), 16, 0, 0)

#define BAR() __builtin_amdgcn_s_barrier()
#define SCHED0() __builtin_amdgcn_sched_barrier(0)
#define VMC(N)                                                                 \
  do {                                                                         \
    asm volatile("s_waitcnt vmcnt(" #N ")" ::: "memory");                      \
  } while (0)

// ---------------------------------------------------------------------------
// Projections (both Q and K in one launch; z selects). Out = X @ W^T + bias,
// 128x128 tile, BK=64, 4 waves. LDS uses 16B-slot XOR swizzle (slot ^= row&7).
__global__ __launch_bounds__(256) void proj_kernel(const float* __restrict__ Xq,
                                                   const float* __restrict__ Wq,
                                                   const float* __restrict__ bq,
                                                   ushort_t* __restrict__ Oq,
                                                   const float* __restrict__ Xk,
                                                   const float* __restrict__ Wk,
                                                   const float* __restrict__ bk,
                                                   ushort_t* __restrict__ Ok) {
  const float* X = blockIdx.z ? Xk : Xq;
  const float* W = blockIdx.z ? Wk : Wq;
  const float* bias = blockIdx.z ? bk : bq;
  ushort_t* Out = blockIdx.z ? Ok : Oq;

  __shared__ __align__(16) ushort_t As[128 * 64];
  __shared__ __align__(16) ushort_t Bs[128 * 64];
  const int tid = threadIdx.x;
  const int wave = tid >> 6, lane = tid & 63;
  const int wr = wave >> 1, wc = wave & 1;
  const int m0 = blockIdx.y * 128, n0 = blockIdx.x * 128;
  const int arow = lane & 15, g = lane >> 4;

  f32x4 acc[4][4] = {};

  for (int kt = 0; kt < 8; ++kt) {
    const int k0 = kt * 64;
#pragma unroll
    for (int i = 0; i < 8; i++) {
      int e = i * 1024 + tid * 4;
      int r = e >> 6, c = e & 63;
      int cs = ((((c >> 3) ^ (r & 7)) << 3) | (c & 7));
      float4 va = *(const float4*)&X[(size_t)(m0 + r) * DN + k0 + c];
      ushort4 ha;
      ha.x = f2bf(va.x); ha.y = f2bf(va.y); ha.z = f2bf(va.z); ha.w = f2bf(va.w);
      *(ushort4*)&As[r * 64 + cs] = ha;
      float4 vb = *(const float4*)&W[(size_t)(n0 + r) * DN + k0 + c];
      ushort4 hb;
      hb.x = f2bf(vb.x); hb.y = f2bf(vb.y); hb.z = f2bf(vb.z); hb.w = f2bf(vb.w);
      *(ushort4*)&Bs[r * 64 + cs] = hb;
    }
    __syncthreads();

    bf16x8 af[4][2], bfr[4][2];
#pragma unroll
    for (int mi = 0; mi < 4; mi++)
#pragma unroll
      for (int ks = 0; ks < 2; ks++)
        af[mi][ks] = *(const bf16x8*)&As[(wr * 64 + mi * 16 + arow) * 64 +
                                         ((((ks << 2) | g) ^ (arow & 7)) << 3)];
#pragma unroll
    for (int ni = 0; ni < 4; ni++)
#pragma unroll
      for (int ks = 0; ks < 2; ks++)
        bfr[ni][ks] = *(const bf16x8*)&Bs[(wc * 64 + ni * 16 + arow) * 64 +
                                          ((((ks << 2) | g) ^ (arow & 7)) << 3)];
#pragma unroll
    for (int ks = 0; ks < 2; ks++)
#pragma unroll
      for (int mi = 0; mi < 4; mi++)
#pragma unroll
        for (int ni = 0; ni < 4; ni++)
          acc[mi][ni] = __builtin_amdgcn_mfma_f32_16x16x32_bf16(
              af[mi][ks], bfr[ni][ks], acc[mi][ni], 0, 0, 0);
    __syncthreads();
  }

  float bc[4];
#pragma unroll
  for (int ni = 0; ni < 4; ni++) bc[ni] = bias[n0 + wc * 64 + ni * 16 + arow];
#pragma unroll
  for (int mi = 0; mi < 4; mi++)
#pragma unroll
    for (int ni = 0; ni < 4; ni++)
#pragma unroll
      for (int j = 0; j < 4; j++) {
        int row = m0 + wr * 64 + mi * 16 + (lane >> 4) * 4 + j;
        int col = n0 + wc * 64 + ni * 16 + arow;
        Out[(size_t)row * DN + col] = f2bf(acc[mi][ni][j] + bc[ni]);
      }
}

// ---------------------------------------------------------------------------
// Pairwise logits + fused max/sum reductions.
// 128x128 output tile (2 a's x 2 b's), 4 waves (2x2), per-wave 64x64 = one
// (a,b) pair. acc = 64 AGPR, ~170 total regs. LDS: double-buffered
// (128A+128B)x64 bf16 = 64 KiB -> TWO blocks per CU. The two co-resident
// blocks are independent barrier groups: one block's MFMA phase overlaps the
// other's stage/drain (m114 co-scheduling) -- the mechanism every 1-block/CU
// variant (r2-r10) lacked. Per K-tile: issue next-buffer stages at top,
// 16 ds_reads + 32 MFMA, then VMC(0)+BAR (single barrier; dbuf-audited).
// Grid 4096 = 64x64 tiles, 8 gens of 512; XCD 8x8 rect per gen (~2MB/L2).
__global__ __launch_bounds__(256, 2) void pairs_kernel(const ushort_t* __restrict__ Q,
                                                       const ushort_t* __restrict__ Km,
                                                       const float* __restrict__ amask,
                                                       const float* __restrict__ ls_ptr,
                                                       float* __restrict__ out) {
  __shared__ __align__(16) ushort_t lds[4 * 128 * 64];  // 64 KiB
  const int tid = threadIdx.x;
  const int wave = tid >> 6, lane = tid & 63;
  const int wr = wave >> 1, wc = wave & 1;      // 2M x 2N wave grid
  const int arow = lane & 15, g = lane >> 4;

  const int bid = blockIdx.x;
  const int xcd = bid & 7, local = (bid >> 3) & 63, gen = bid >> 9;
  const int by = gen * 8 + (local >> 3);        // 0..63
  const int bx = xcd * 8 + (local & 7);         // 0..63

  const int l8 = lane >> 3, l7 = lane & 7;
  const int srcSlot = l7 ^ l8;

  // epilogue scalars first; drain their vmem so pipeline vmcnt counts are exact
  const float lsv = expf(ls_ptr[0]);
  float amv;
  {
    float am = amask[(by * 2 + wr) * 64 + lane];
#pragma unroll
    for (int off = 1; off < 64; off <<= 1) am += __shfl_xor(am, off);
    amv = am;
  }
  VMC(0); SCHED0();

  f32x4 acc[4][4] = {};

  // staging pointers: each wave stages 32 rows (4 x gll16) of A and of B
  const ushort_t* pA = Q + (size_t)(by * 128 + wave * 32 + l8) * DN + srcSlot * 8;
  const ushort_t* pB = Km + (size_t)(bx * 128 + wave * 32 + l8) * DN + srcSlot * 8;
  const int sR = wave * 32;                     // LDS row base for this wave

  auto ST = [&](int dn) {
#pragma unroll
    for (int u = 0; u < 4; u++)
      GLL16(pA + (u * 8) * DN, &lds[((dn * 2 + 0) * 128 + sR + u * 8) * 64]);
#pragma unroll
    for (int u = 0; u < 4; u++)
      GLL16(pB + (u * 8) * DN, &lds[((dn * 2 + 1) * 128 + sR + u * 8) * 64]);
    pA += 64; pB += 64;
  };
  auto KSTEP = [&](int d, int ks) {
    bf16x8 aF[4], bF[4];
#pragma unroll
    for (int mi = 0; mi < 4; mi++) {
      int row = wr * 64 + mi * 16 + arow;
      int slt = ((ks << 2) | g) ^ (arow & 7);
      aF[mi] = *(const bf16x8*)&lds[((d * 2 + 0) * 128 + row) * 64 + slt * 8];
    }
#pragma unroll
    for (int ni = 0; ni < 4; ni++) {
      int row = wc * 64 + ni * 16 + arow;
      int slt = ((ks << 2) | g) ^ (arow & 7);
      bF[ni] = *(const bf16x8*)&lds[((d * 2 + 1) * 128 + row) * 64 + slt * 8];
    }
#pragma unroll
    for (int mi = 0; mi < 4; mi++)
#pragma unroll
      for (int ni = 0; ni < 4; ni++)
        acc[mi][ni] = __builtin_amdgcn_mfma_f32_16x16x32_bf16(
            aF[mi], bF[ni], acc[mi][ni], 0, 0, 0);
  };

  // prologue: stage tile 0 into buffer 0, publish
  ST(0);
  VMC(0);
  BAR(); SCHED0();

#pragma unroll
  for (int k = 0; k < 8; ++k) {
    const int d = k & 1;
    if (k < 7) ST(d ^ 1);          // issue-early into the other buffer
    KSTEP(d, 0);
    KSTEP(d, 1);
    if (k < 7) {
      VMC(0);                      // stages issued ~1 body ago: mostly landed
      BAR(); SCHED0();             // publish buffer d^1; reads of d all done
    }
  }

  // ---- fused epilogue: one (a,b) pair per wave ----
  // C/D layout: col = lane&15, row = (lane>>4)*4 + reg.
  float t2v = 0.f;
#pragma unroll
  for (int mi = 0; mi < 4; mi++) {
    f32x4 rm = acc[mi][0];
#pragma unroll
    for (int ni = 1; ni < 4; ni++)
#pragma unroll
      for (int j = 0; j < 4; j++) rm[j] = fmaxf(rm[j], acc[mi][ni][j]);
#pragma unroll
    for (int off = 1; off < 16; off <<= 1)
#pragma unroll
      for (int j = 0; j < 4; j++) rm[j] = fmaxf(rm[j], __shfl_xor(rm[j], off));
    t2v += rm[0] + rm[1] + rm[2] + rm[3];
  }
  t2v += __shfl_xor(t2v, 16);
  t2v += __shfl_xor(t2v, 32);

  float v2t = 0.f;
#pragma unroll
  for (int ni = 0; ni < 4; ni++) {
    float cm = -INFINITY;
#pragma unroll
    for (int mi = 0; mi < 4; mi++)
#pragma unroll
      for (int j = 0; j < 4; j++) cm = fmaxf(cm, acc[mi][ni][j]);
    cm = fmaxf(cm, __shfl_xor(cm, 16));
    cm = fmaxf(cm, __shfl_xor(cm, 32));
    v2t += cm;
  }
#pragma unroll
  for (int off = 1; off < 16; off <<= 1) v2t += __shfl_xor(v2t, off);

  const int a = by * 2 + wr, b = bx * 2 + wc;
  float r = lsv * 0.5f * (t2v / amv + v2t / 64.0f);
  if (lane == 0) {
    out[a * NB + b] = r;                 // r
    out[NB * NB + b * NB + a] = r;       // r.T
  }
}

// ---------------------------------------------------------------------------
extern "C" void kernel_launch(void* const* d_in, const int* in_sizes, int n_in,
                              void* d_out, int out_size, void* d_ws, size_t ws_size,
                              hipStream_t stream) {
  const float* query = (const float*)d_in[0];
  const float* key   = (const float*)d_in[1];
  const float* amask = (const float*)d_in[2];
  const float* Wq    = (const float*)d_in[3];
  const float* bq    = (const float*)d_in[4];
  const float* Wk    = (const float*)d_in[5];
  const float* bk    = (const float*)d_in[6];
  const float* ls    = (const float*)d_in[7];

  char* ws = (char*)d_ws;
  ushort_t* Qb = (ushort_t*)(ws);                      // 8 MB
  ushort_t* Kb = (ushort_t*)(ws + 8 * 1024 * 1024);    // 8 MB

  proj_kernel<<<dim3(4, 64, 2), 256, 0, stream>>>(query, Wq, bq, Qb, key, Wk, bk, Kb);
  pairs_kernel<<<dim3(4096), 256, 0, stream>>>(Qb, Kb, amask, ls, (float*)d_out);
}

// Round 12
// 94.143 us; speedup vs baseline: 1.7773x; 1.2152x over previous
//
#include <hip/hip_runtime.h>
#include <math.h>

// Problem constants: N=128, LQ=LK=64, D=512, H=8 (head split is a no-op in the einsum).
#define DN 512          // feature dim
#define NB 128          // batch N

typedef unsigned short ushort_t;
typedef __attribute__((ext_vector_type(8))) short bf16x8;
typedef __attribute__((ext_vector_type(4))) float f32x4;

static __device__ __forceinline__ ushort_t f2bf(float f){
  unsigned u = __float_as_uint(f);
  u += 0x7fffu + ((u >> 16) & 1u);   // round-to-nearest-even
  return (ushort_t)(u >> 16);
}

// async global->LDS, 16B per lane; LDS dest is wave-uniform base + lane*16
#define GLL16(gp, lp)                                                          \
  __builtin_amdgcn_global_load_lds(                                            \
      (const __attribute__((address_space(1))) void*)(gp),                     \
      (__attribute__((address_space(3))) void*)(lp), 16, 0, 0)

#define BAR() __builtin_amdgcn_s_barrier()
#define SCHED0() __builtin_amdgcn_sched_barrier(0)
#define VMC(N)                                                                 \
  do {                                                                         \
    asm volatile("s_waitcnt vmcnt(" #N ")" ::: "memory");                      \
  } while (0)

// ---------------------------------------------------------------------------
// Projections (both Q and K in one launch). Out = X @ W^T + bias, 128x128
// tile, BK=64, 4 waves, LDS 16B-slot XOR swizzle (slot ^= row&7).
// Block decode groups the 4 n-blocks sharing an X m-tile onto the SAME XCD
// in the SAME dispatch round (fids spaced 64 apart; 512 blocks = 2 rounds):
// per-XCD round working set = 8 X-tiles (2MB) + 4 W-tiles (1MB) = 3MB < 4MB
// L2 -> X fetched from HBM once instead of ~4x (the round-11 diagnosis).
__global__ __launch_bounds__(256) void proj_kernel(const float* __restrict__ Xq,
                                                   const float* __restrict__ Wq,
                                                   const float* __restrict__ bq,
                                                   ushort_t* __restrict__ Oq,
                                                   const float* __restrict__ Xk,
                                                   const float* __restrict__ Wk,
                                                   const float* __restrict__ bk,
                                                   ushort_t* __restrict__ Ok) {
  const int fid = blockIdx.x;                  // 0..511
  const int xcd = fid & 7, local = fid >> 3;   // 64 locals per XCD
  const int mt = xcd * 8 + (local & 7);        // 0..63 (m-tile)
  const int nt = (local >> 3) & 3;             // 0..3  (n-tile)
  const int zz = local >> 5;                   // 0 = Q (round 1), 1 = K (round 2)

  const float* X = zz ? Xk : Xq;
  const float* W = zz ? Wk : Wq;
  const float* bias = zz ? bk : bq;
  ushort_t* Out = zz ? Ok : Oq;

  __shared__ __align__(16) ushort_t As[128 * 64];
  __shared__ __align__(16) ushort_t Bs[128 * 64];
  const int tid = threadIdx.x;
  const int wave = tid >> 6, lane = tid & 63;
  const int wr = wave >> 1, wc = wave & 1;
  const int m0 = mt * 128, n0 = nt * 128;
  const int arow = lane & 15, g = lane >> 4;

  f32x4 acc[4][4] = {};

  for (int kt = 0; kt < 8; ++kt) {
    const int k0 = kt * 64;
#pragma unroll
    for (int i = 0; i < 8; i++) {
      int e = i * 1024 + tid * 4;
      int r = e >> 6, c = e & 63;
      int cs = ((((c >> 3) ^ (r & 7)) << 3) | (c & 7));
      float4 va = *(const float4*)&X[(size_t)(m0 + r) * DN + k0 + c];
      ushort4 ha;
      ha.x = f2bf(va.x); ha.y = f2bf(va.y); ha.z = f2bf(va.z); ha.w = f2bf(va.w);
      *(ushort4*)&As[r * 64 + cs] = ha;
      float4 vb = *(const float4*)&W[(size_t)(n0 + r) * DN + k0 + c];
      ushort4 hb;
      hb.x = f2bf(vb.x); hb.y = f2bf(vb.y); hb.z = f2bf(vb.z); hb.w = f2bf(vb.w);
      *(ushort4*)&Bs[r * 64 + cs] = hb;
    }
    __syncthreads();

    bf16x8 af[4][2], bfr[4][2];
#pragma unroll
    for (int mi = 0; mi < 4; mi++)
#pragma unroll
      for (int ks = 0; ks < 2; ks++)
        af[mi][ks] = *(const bf16x8*)&As[(wr * 64 + mi * 16 + arow) * 64 +
                                         ((((ks << 2) | g) ^ (arow & 7)) << 3)];
#pragma unroll
    for (int ni = 0; ni < 4; ni++)
#pragma unroll
      for (int ks = 0; ks < 2; ks++)
        bfr[ni][ks] = *(const bf16x8*)&Bs[(wc * 64 + ni * 16 + arow) * 64 +
                                          ((((ks << 2) | g) ^ (arow & 7)) << 3)];
#pragma unroll
    for (int ks = 0; ks < 2; ks++)
#pragma unroll
      for (int mi = 0; mi < 4; mi++)
#pragma unroll
        for (int ni = 0; ni < 4; ni++)
          acc[mi][ni] = __builtin_amdgcn_mfma_f32_16x16x32_bf16(
              af[mi][ks], bfr[ni][ks], acc[mi][ni], 0, 0, 0);
    __syncthreads();
  }

  float bc[4];
#pragma unroll
  for (int ni = 0; ni < 4; ni++) bc[ni] = bias[n0 + wc * 64 + ni * 16 + arow];
#pragma unroll
  for (int mi = 0; mi < 4; mi++)
#pragma unroll
    for (int ni = 0; ni < 4; ni++)
#pragma unroll
      for (int j = 0; j < 4; j++) {
        int row = m0 + wr * 64 + mi * 16 + (lane >> 4) * 4 + j;
        int col = n0 + wc * 64 + ni * 16 + arow;
        Out[(size_t)row * DN + col] = f2bf(acc[mi][ni][j] + bc[ni]);
      }
}

// ---------------------------------------------------------------------------
// Pairwise logits + fused max/sum reductions. One 256x256 output tile per
// block (4 a's x 4 b's), 8 waves (2M x 4N), K-loop 8 tiles of BK=64 with
// double-buffered LDS, one barrier per K-tile + mid-tile barrier, counted
// vmcnt (never 0 in the steady state). XCD-rectangle block swizzle.
// == round-4 champion, byte-identical ==
__global__ __launch_bounds__(512, 2) void pairs_kernel(const ushort_t* __restrict__ Q,
                                                       const ushort_t* __restrict__ Km,
                                                       const float* __restrict__ amask,
                                                       const float* __restrict__ ls_ptr,
                                                       float* __restrict__ out) {
  __shared__ __align__(16) ushort_t lds[2 * 2 * 256 * 64];  // 128 KiB
  const int tid = threadIdx.x;
  const int wave = tid >> 6, lane = tid & 63;
  const int wr = wave >> 2, wc = wave & 3;
  const int arow = lane & 15, g = lane >> 4;

  const int bid = blockIdx.x;
  const int gen = bid >> 8, slot = bid & 255;
  const int xcd = slot & 7, idx = slot >> 3;
  const int by = ((gen & 1) << 4) + ((xcd >> 1) << 2) + (idx >> 3);
  const int bx = ((gen >> 1) << 4) + ((xcd & 1) << 3) + (idx & 7);

  const int l8 = lane >> 3, l7 = lane & 7;
  const int srcSlot = l7 ^ l8;

  // epilogue scalars first; force their vmem drained before the pipeline
  const float lsv = expf(ls_ptr[0]);
  float am2[2];
#pragma unroll
  for (int ph = 0; ph < 2; ph++) {
    float am = amask[(by * 4 + wr * 2 + ph) * 64 + lane];
#pragma unroll
    for (int off = 1; off < 64; off <<= 1) am += __shfl_xor(am, off);
    am2[ph] = am;
  }
  VMC(0); SCHED0();   // no stray loads outstanding: vmcnt counts below are exact

  f32x4 acc[8][4] = {};
  bf16x8 aA[4], aB[4], bR0[4], bR1[4];

  // stage A unit u (u0: rows 0-63 & 128-191; u1: rows 64-127 & 192-255)
  auto SA = [&](int u, int k, int d) {
    int base = (wave >> 2) * 128 + u * 64 + (wave & 3) * 16;
#pragma unroll
    for (int i = 0; i < 2; i++) {
      int row = base + i * 8;
      GLL16(Q + (size_t)(by * 256 + row + l8) * DN + k * 64 + srcSlot * 8,
            &lds[((d * 2 + 0) * 256 + row) * 64]);
    }
  };
  auto SB = [&](int half, int k, int d) {
#pragma unroll
    for (int i = 0; i < 2; i++) {
      int row = half * 128 + wave * 16 + i * 8;
      GLL16(Km + (size_t)(bx * 256 + row + l8) * DN + k * 64 + srcSlot * 8,
            &lds[((d * 2 + 1) * 256 + row) * 64]);
    }
  };
  auto LDA = [&](bf16x8* ar, int mh, int ks, int d) {
#pragma unroll
    for (int mi = 0; mi < 4; mi++) {
      int row = wr * 128 + (mh * 4 + mi) * 16 + arow;
      int slt = ((ks << 2) | g) ^ (arow & 7);
      ar[mi] = *(const bf16x8*)&lds[((d * 2 + 0) * 256 + row) * 64 + slt * 8];
    }
  };
  auto LDB = [&](bf16x8* br, int ks, int d) {
#pragma unroll
    for (int ni = 0; ni < 4; ni++) {
      int row = wc * 64 + ni * 16 + arow;
      int slt = ((ks << 2) | g) ^ (arow & 7);
      br[ni] = *(const bf16x8*)&lds[((d * 2 + 1) * 256 + row) * 64 + slt * 8];
    }
  };
  auto MMA = [&](int mh, bf16x8* ar, bf16x8* br) {
    __builtin_amdgcn_s_setprio(1);
#pragma unroll
    for (int mi = 0; mi < 4; mi++)
#pragma unroll
      for (int ni = 0; ni < 4; ni++)
        acc[mh * 4 + mi][ni] = __builtin_amdgcn_mfma_f32_16x16x32_bf16(
            ar[mi], br[ni], acc[mh * 4 + mi][ni], 0, 0, 0);
    __builtin_amdgcn_s_setprio(0);
  };

  // prologue: stage tile 0 fully; wait {B-lo,B-hi,A-u0}, leave A-u1 in flight
  SB(0, 0, 0); SB(1, 0, 0); SA(0, 0, 0); SA(1, 0, 0);
  VMC(2);
  BAR(); SCHED0();

#pragma unroll
  for (int k = 0; k < 8; ++k) {
    const int d = k & 1, dn = d ^ 1;
    const bool doST = (k < 7);
    // issue next tile's 8 stage loads first (issue-early, land-late)
    if (doST) { SB(0, k + 1, dn); SB(1, k + 1, dn); SA(0, k + 1, dn); SA(1, k + 1, dn); }
    // mh=0 halves (rows in A-u0; B validated at boundary)
    LDB(bR0, 0, d); LDB(bR1, 1, d);
    LDA(aA, 0, 0, d); MMA(0, aA, bR0);
    LDA(aB, 0, 1, d); MMA(0, aB, bR1);
    // A-u1 of THIS tile was left in flight: validate (waits 2 oldest)
    if (doST) { VMC(8); } else { VMC(0); }
    BAR();
    LDA(aA, 1, 0, d); MMA(1, aA, bR0);
    LDA(aB, 1, 1, d); MMA(1, aB, bR1);
    // boundary: next tile's {B-lo,B-hi,A-u0} done, leave its A-u1 in flight
    if (doST) { VMC(2); }
    BAR(); SCHED0();
  }

  // ---- fused epilogue: two (a,b) pairs per wave ----
  // C/D layout: col = lane&15, row = (lane>>4)*4 + reg.
#pragma unroll
  for (int ph = 0; ph < 2; ph++) {
    float t2v = 0.f;
#pragma unroll
    for (int mi = ph * 4; mi < ph * 4 + 4; mi++) {
      f32x4 rm = acc[mi][0];
#pragma unroll
      for (int ni = 1; ni < 4; ni++)
#pragma unroll
        for (int j = 0; j < 4; j++) rm[j] = fmaxf(rm[j], acc[mi][ni][j]);
#pragma unroll
      for (int off = 1; off < 16; off <<= 1)
#pragma unroll
        for (int j = 0; j < 4; j++) rm[j] = fmaxf(rm[j], __shfl_xor(rm[j], off));
      t2v += rm[0] + rm[1] + rm[2] + rm[3];
    }
    t2v += __shfl_xor(t2v, 16);
    t2v += __shfl_xor(t2v, 32);

    float v2t = 0.f;
#pragma unroll
    for (int ni = 0; ni < 4; ni++) {
      float cm = -INFINITY;
#pragma unroll
      for (int mi = ph * 4; mi < ph * 4 + 4; mi++)
#pragma unroll
        for (int j = 0; j < 4; j++) cm = fmaxf(cm, acc[mi][ni][j]);
      cm = fmaxf(cm, __shfl_xor(cm, 16));
      cm = fmaxf(cm, __shfl_xor(cm, 32));
      v2t += cm;
    }
#pragma unroll
    for (int off = 1; off < 16; off <<= 1) v2t += __shfl_xor(v2t, off);

    const int a = by * 4 + wr * 2 + ph, b = bx * 4 + wc;
    float r = lsv * 0.5f * (t2v / am2[ph] + v2t / 64.0f);
    if (lane == 0) {
      out[a * NB + b] = r;                 // r
      out[NB * NB + b * NB + a] = r;       // r.T
    }
  }
}

// ---------------------------------------------------------------------------
extern "C" void kernel_launch(void* const* d_in, const int* in_sizes, int n_in,
                              void* d_out, int out_size, void* d_ws, size_t ws_size,
                              hipStream_t stream) {
  const float* query = (const float*)d_in[0];
  const float* key   = (const float*)d_in[1];
  const float* amask = (const float*)d_in[2];
  const float* Wq    = (const float*)d_in[3];
  const float* bq    = (const float*)d_in[4];
  const float* Wk    = (const float*)d_in[5];
  const float* bk    = (const float*)d_in[6];
  const float* ls    = (const float*)d_in[7];

  char* ws = (char*)d_ws;
  ushort_t* Qb = (ushort_t*)(ws);                      // 8 MB
  ushort_t* Kb = (ushort_t*)(ws + 8 * 1024 * 1024);    // 8 MB

  proj_kernel<<<dim3(512), 256, 0, stream>>>(query, Wq, bq, Qb, key, Wk, bk, Kb);
  pairs_kernel<<<dim3(1024), 512, 0, stream>>>(Qb, Kb, amask, ls, (float*)d_out);
}